// Round 12
// baseline (146.930 us; speedup 1.0000x reference)
//
#include <hip/hip_runtime.h>
#include <math.h>

#define B_  8
#define C_  64
#define H_  128
#define W_  128
#define KK_ 9
#define CO_ 64
#define HW_ (H_*W_)
#define CK_ 576

typedef _Float16 f16x8 __attribute__((ext_vector_type(8)));
typedef _Float16 h2    __attribute__((ext_vector_type(2)));
typedef __attribute__((ext_vector_type(4))) float f32x4;

__device__ inline unsigned pkrtz(float a, float b){
    auto v = __builtin_amdgcn_cvt_pkrtz(a, b);   // __fp16x2 on this toolchain
    union{decltype(v) h; unsigned u;} c; c.h = v; return c.u;
}
__device__ inline h2 u2h(unsigned u){ union{unsigned x; h2 h;} c; c.x = u; return c.h; }
__device__ inline unsigned h2u(h2 v){ union{h2 h; unsigned u;} c; c.h = v; return c.u; }
__device__ inline unsigned short f2h(float f){
    _Float16 h = (_Float16)f;
    union{_Float16 h; unsigned short s;} c; c.h = h; return c.s;
}
// broadcast lo/hi f16 of a dword into both halves (1 v_perm_b32 each)
__device__ inline h2 bcast_lo(unsigned u){ return u2h(__builtin_amdgcn_perm(u, u, 0x01000100)); }
__device__ inline h2 bcast_hi(unsigned u){ return u2h(__builtin_amdgcn_perm(u, u, 0x03020302)); }

// ---- transpose_prep: fused x NCHW->NHWC f16 transpose + weight repack ----
__global__ __launch_bounds__(256) void transpose_prep(
    const float* __restrict__ x, unsigned short* __restrict__ xt,
    const float* __restrict__ w_dcn, const float* __restrict__ w_off,
    unsigned short* __restrict__ w_bf, unsigned short* __restrict__ wA)
{
    __shared__ unsigned tb[64 * 33];          // [pix][ch-pair], stride 33
    if (blockIdx.x >= B_ * 256) {             // weight-repack tail blocks
        int i = (blockIdx.x - B_ * 256) * 256 + threadIdx.x;
        if (i < 64 * CK_) {
            int o = i / CK_, r = i % CK_;
            int tap = r >> 6, c = r & 63;
            w_bf[i] = f2h(w_dcn[o * CK_ + c * 9 + tap]);
        } else {
            int j = i - 64 * CK_;             // 0 .. 32*576-1
            int o = j / CK_, r = j % CK_;
            int tap = r >> 6, c = r & 63;
            float v = (o < 27) ? w_off[o * CK_ + c * 9 + tap] : 0.f;
            wA[j] = f2h(v);
        }
        return;
    }
    int b = blockIdx.x >> 8;
    int pixbase = (blockIdx.x & 255) * 64;
    int t = threadIdx.x;
    #pragma unroll
    for (int i = 0; i < 2; ++i) {
        int idx = i * 256 + t;                // 0..511
        int cp = idx >> 4;                    // ch-pair 0..31
        int p4 = (idx & 15) * 4;              // pix 0..60 step 4
        const float* r0 = x + ((size_t)(b * C_) + 2 * cp    ) * HW_ + pixbase + p4;
        const float* r1 = x + ((size_t)(b * C_) + 2 * cp + 1) * HW_ + pixbase + p4;
        float4 f0 = *(const float4*)r0;
        float4 f1 = *(const float4*)r1;
        tb[(p4 + 0) * 33 + cp] = pkrtz(f0.x, f1.x);
        tb[(p4 + 1) * 33 + cp] = pkrtz(f0.y, f1.y);
        tb[(p4 + 2) * 33 + cp] = pkrtz(f0.z, f1.z);
        tb[(p4 + 3) * 33 + cp] = pkrtz(f0.w, f1.w);
    }
    __syncthreads();
    unsigned* xo = (unsigned*)xt + ((size_t)b * HW_ + pixbase) * 32;
    #pragma unroll
    for (int i = 0; i < 2; ++i) {
        int idx = i * 256 + t;
        int pix = idx >> 3, j = idx & 7;
        uint4 v;
        v.x = tb[pix * 33 + j * 4 + 0];
        v.y = tb[pix * 33 + j * 4 + 1];
        v.z = tb[pix * 33 + j * 4 + 2];
        v.w = tb[pix * 33 + j * 4 + 3];
        *(uint4*)(xo + pix * 32 + j * 4) = v;   // contiguous 1KB per wave-instr
    }
}

// ==== ROUND 12: dcn15 + LDS diet for 5 blocks/CU (single-variable) =========
// dcn15 (67.5us) uses 35840B LDS -> 4 blocks/CU. Halo pixel stride 144->128B
// with per-pixel chunk XOR swizzle (g' = g ^ (c&7)): same bytes, bijective
// within each pixel's 128B, applied identically on staging-write and tap-read
// -> bit-exact; staging coalescing unchanged. Union(halo 25344, om 7020,
// sS 25600) = 25600; +scr 6912 = 32512 -> alloc 32768 = exactly 5 x 32KiB =
// 160KiB -> 5 blocks/CU. launch_bounds (256,5); VGPR 56 well under the
// 102-reg 5-wave budget. Everything else byte-identical to dcn15.
// Pre-commit: occupancy>=44 & dur<=63 -> TLP lever real; both unmoved ->
// third clean null on LDS-occupancy: decomposition at structural floor.

#define PXB 128                               // bytes per staged halo pixel
#define ROWB (66 * PXB)                       // 8448 B per staged row
#define SSTR4 400                             // sS row stride bytes

__global__ __launch_bounds__(256, 5) void dcn16(
    const unsigned short* __restrict__ xt,    // f16 NHWC
    const unsigned short* __restrict__ wA,    // offset-conv weights [32][576] f16
    const float* __restrict__ b_off,
    const unsigned short* __restrict__ w_bf,  // dcn weights [64][576] f16
    float* __restrict__ out)
{
    __shared__ __align__(16) unsigned char uni[25600];  // halo | om | sS union
    __shared__ uint2 scr_w[576];              // 4608 B, live through Phase B
    __shared__ int   scr_o[576];              // 2304 B
    unsigned char* xrow = uni;                // 25344 B halo
    float* om = (float*)uni;                  // 7020 B after Phase A (barrier)
    unsigned char* sS = uni;                  // 25600 B in Phase B

    int tile = blockIdx.x;
    int b  = tile >> 8;
    int p0 = (tile & 255) * 64;
    int y  = p0 >> 7;
    int x0 = p0 & 127;
    int t  = threadIdx.x;
    int lane = t & 63, w = t >> 6;
    int m = lane & 15, q = lane >> 4;

    const unsigned short* xbr = xt + (size_t)(b * HW_) * 64;

    // ---- stage halo: rows y-1..y+1, cols x0-1..x0+64, zeros out of range.
    // Chunk g of pixel c stored at (g ^ (c&7))*16 within the pixel's 128B. ---
    for (int i = t; i < 3 * 66 * 8; i += 256) {
        int r = i / 528;                      // 0..2
        int rem = i - r * 528;
        int c = rem >> 3;                     // 0..65
        int g = rem & 7;                      // 16B chunk within pixel
        int yy = y - 1 + r;
        int xx = x0 - 1 + c;
        uint4 v = {0, 0, 0, 0};
        if (yy >= 0 && yy < H_ && xx >= 0 && xx < W_)
            v = *(const uint4*)(xbr + ((size_t)yy * W_ + xx) * 64 + g * 8);
        *(uint4*)(xrow + r * ROWB + c * PXB + ((g ^ (c & 7)) << 4)) = v;
    }
    __syncthreads();

    // ---- Phase A: offset conv; B-operand from swizzled LDS halo ------------
    {
        int o0c = (w & 1) * 16;
        int pxh = (w >> 1) * 32;

        f32x4 accc[2] = {};
        #pragma unroll
        for (int ky = 0; ky < 3; ++ky) {
            #pragma unroll
            for (int kx = 0; kx < 3; ++kx) {
                int s2 = (ky * 3 + kx) * 2;
                f16x8 A0 = *(const f16x8*)(wA + (o0c + m) * CK_ + s2 * 32 + q * 8);
                f16x8 A1 = *(const f16x8*)(wA + (o0c + m) * CK_ + (s2 + 1) * 32 + q * 8);
                #pragma unroll
                for (int nt = 0; nt < 2; ++nt) {
                    int c = pxh + nt * 16 + m + kx;   // staged col (0..65)
                    const unsigned char* p = xrow + ky * ROWB + c * PXB;
                    int off0 = (q ^ (c & 7)) << 4;    // chunk q (ch q*8..+7)
                    f16x8 b0 = *(const f16x8*)(p + off0);
                    f16x8 b1 = *(const f16x8*)(p + (off0 ^ 64));  // chunk q+4
                    accc[nt] = __builtin_amdgcn_mfma_f32_16x16x32_f16(A0, b0, accc[nt], 0, 0, 0);
                    accc[nt] = __builtin_amdgcn_mfma_f32_16x16x32_f16(A1, b1, accc[nt], 0, 0, 0);
                }
            }
        }
        __syncthreads();      // halo dead; om about to overwrite the region
        #pragma unroll
        for (int nt = 0; nt < 2; ++nt) {
            #pragma unroll
            for (int r = 0; r < 4; ++r) {
                int j = o0c + q * 4 + r;
                if (j < 27)
                    om[j * 65 + pxh + nt * 16 + m] = accc[nt][r] + b_off[j];
            }
        }
    }
    __syncthreads();

    // ---- Phase 0: offsets -> 4xf16 weights + packed offsets (LDS scr) ------
    for (int i = t; i < 576; i += 256) {
        int k = i >> 6, sp = i & 63;
        float dy = om[(2 * k)     * 65 + sp];
        float dx = om[(2 * k + 1) * 65 + sp];
        float mk = 1.f / (1.f + __expf(-om[(18 + k) * 65 + sp]));
        float py = dy + (float)(y - 1 + k / 3);
        float px = dx + (float)(x0 + sp - 1 + k % 3);
        float fy = floorf(py), fx = floorf(px);
        int iy = (int)fy, ix = (int)fx;
        float ay = py - fy, ax = px - fx;
        float wy0 = (iy >= 0  && iy < H_)     ? (1.f - ay) : 0.f;
        float wy1 = (iy >= -1 && iy < H_ - 1) ? ay         : 0.f;
        float wx0 = (ix >= 0  && ix < W_)     ? (1.f - ax) : 0.f;
        float wx1 = (ix >= -1 && ix < W_ - 1) ? ax         : 0.f;
        int iy0 = min(max(iy, 0), H_ - 1);
        int iy1 = min(max(iy + 1, 0), H_ - 1);
        int ix0 = min(max(ix, 0), W_ - 1);
        int ix1 = min(max(ix + 1, 0), W_ - 1);
        float w00 = wy0*wx0*mk, w01 = wy0*wx1*mk, w10 = wy1*wx0*mk, w11 = wy1*wx1*mk;
        uint2 wv;
        wv.x = pkrtz(w00, w01);               // lo=w00 hi=w01
        wv.y = pkrtz(w10, w11);               // lo=w10 hi=w11
        scr_w[i] = wv;
        int off00 = (iy0 * W_ + ix0) * 128;   // bytes (64ch * 2B f16)
        scr_o[i] = off00 | ((ix1 != ix0) << 22) | ((iy1 != iy0) << 23);
    }

    int o0 = w * 16;
    __syncthreads();        // scr ready; om region (sS) now free

    // ---- Phase B: verbatim dcn12/dcn15 rolling pipeline --------------------
    int cq = lane & 7;
    int g  = lane >> 3;
    const unsigned char* xb = (const unsigned char*)xbr;
    f32x4 acc[4] = {};
    int piB = w * 8 + g;

    uint2 wA_, wB_; int pB_;
    uint4 a00, a01, a10, a11;
    {
        wA_ = scr_w[piB];      int oo = scr_o[piB];
        wB_ = scr_w[piB + 32]; pB_ = scr_o[piB + 32];
        const unsigned char* a0 = xb + (oo & 0x3FFFFF) + cq * 16;
        int dxb = (oo >> 15) & 128;
        int dyb = (oo >> 9)  & 16384;
        a00 = *(const uint4*)(a0);
        a01 = *(const uint4*)(a0 + dxb);
        a10 = *(const uint4*)(a0 + dyb);
        a11 = *(const uint4*)(a0 + dyb + dxb);
    }

    #pragma unroll
    for (int chunk = 0; chunk < 3; ++chunk) {
        #pragma unroll
        for (int it6 = 0; it6 < 6; ++it6) {
            const int k = chunk * 6 + it6;
            uint2 wC_ = {}; int pC_ = 0;
            if (k + 2 < 18) {
                int P = piB + (k + 2) * 32;
                wC_ = scr_w[P]; pC_ = scr_o[P];
            }
            uint4 n00 = {}, n01 = {}, n10 = {}, n11 = {};
            if (k + 1 < 18) {
                const unsigned char* a0 = xb + (pB_ & 0x3FFFFF) + cq * 16;
                int dxb = (pB_ >> 15) & 128;
                int dyb = (pB_ >> 9)  & 16384;
                n00 = *(const uint4*)(a0);
                n01 = *(const uint4*)(a0 + dxb);
                n10 = *(const uint4*)(a0 + dyb);
                n11 = *(const uint4*)(a0 + dyb + dxb);
            }
            h2 w00 = bcast_lo(wA_.x), w01 = bcast_hi(wA_.x);
            h2 w10 = bcast_lo(wA_.y), w11 = bcast_hi(wA_.y);
            uint4 o4; h2 r;
            r = w00*u2h(a00.x) + w01*u2h(a01.x) + w10*u2h(a10.x) + w11*u2h(a11.x); o4.x = h2u(r);
            r = w00*u2h(a00.y) + w01*u2h(a01.y) + w10*u2h(a10.y) + w11*u2h(a11.y); o4.y = h2u(r);
            r = w00*u2h(a00.z) + w01*u2h(a01.z) + w10*u2h(a10.z) + w11*u2h(a11.z); o4.z = h2u(r);
            r = w00*u2h(a00.w) + w01*u2h(a01.w) + w10*u2h(a10.w) + w11*u2h(a11.w); o4.w = h2u(r);
            int sp  = (piB + (k & 1) * 32) & 63;
            int ktl = it6 >> 1;
            *(uint4*)&sS[sp * SSTR4 + ktl * 128 + cq * 16] = o4;
            wA_ = wB_; wB_ = wC_; pB_ = pC_;
            a00 = n00; a01 = n01; a10 = n10; a11 = n11;
        }
        f16x8 Af[6];
        #pragma unroll
        for (int s = 0; s < 6; ++s)
            Af[s] = *(const f16x8*)(w_bf + (o0 + m) * CK_ + (chunk * 6 + s) * 32 + q * 8);
        __syncthreads();

        #pragma unroll
        for (int s = 0; s < 6; ++s) {
            #pragma unroll
            for (int nt = 0; nt < 4; ++nt) {
                f16x8 bb = *(const f16x8*)&sS[(nt * 16 + m) * SSTR4 + s * 64 + q * 16];
                acc[nt] = __builtin_amdgcn_mfma_f32_16x16x32_f16(Af[s], bb, acc[nt], 0, 0, 0);
            }
        }
        __syncthreads();
    }

    #pragma unroll
    for (int nt = 0; nt < 4; ++nt) {
        #pragma unroll
        for (int r = 0; r < 4; ++r) {
            int o = o0 + q * 4 + r;
            out[((size_t)(b * CO_ + o)) * HW_ + p0 + nt * 16 + m] = acc[nt][r];
        }
    }
}

extern "C" void kernel_launch(void* const* d_in, const int* in_sizes, int n_in,
                              void* d_out, int out_size, void* d_ws, size_t ws_size,
                              hipStream_t stream)
{
    const float* x     = (const float*)d_in[0];
    const float* w_off = (const float*)d_in[1];
    const float* b_off = (const float*)d_in[2];
    const float* w_dcn = (const float*)d_in[3];
    float* out = (float*)d_out;

    unsigned short* xt   = (unsigned short*)d_ws;                // 16.8 MB
    unsigned short* w_bf = xt + (size_t)B_ * HW_ * 64;           // 73.7 KB
    unsigned short* wA   = w_bf + 64 * CK_;                      // 36.9 KB

    transpose_prep<<<B_ * 256 + 216, 256, 0, stream>>>(x, xt, w_dcn, w_off, w_bf, wA);
    dcn16<<<B_ * 256, 256, 0, stream>>>(xt, wA, b_off, w_bf, out);
}

// Round 13
// 146.734 us; speedup vs baseline: 1.0013x; 1.0013x over previous
//
#include <hip/hip_runtime.h>
#include <math.h>

#define B_  8
#define C_  64
#define H_  128
#define W_  128
#define KK_ 9
#define CO_ 64
#define HW_ (H_*W_)
#define CK_ 576

typedef _Float16 f16x8 __attribute__((ext_vector_type(8)));
typedef _Float16 h2    __attribute__((ext_vector_type(2)));
typedef __attribute__((ext_vector_type(4))) float f32x4;

__device__ inline unsigned pkrtz(float a, float b){
    auto v = __builtin_amdgcn_cvt_pkrtz(a, b);   // __fp16x2 on this toolchain
    union{decltype(v) h; unsigned u;} c; c.h = v; return c.u;
}
__device__ inline h2 u2h(unsigned u){ union{unsigned x; h2 h;} c; c.x = u; return c.h; }
__device__ inline unsigned h2u(h2 v){ union{h2 h; unsigned u;} c; c.h = v; return c.u; }
__device__ inline unsigned short f2h(float f){
    _Float16 h = (_Float16)f;
    union{_Float16 h; unsigned short s;} c; c.h = h; return c.s;
}
// broadcast lo/hi f16 of a dword into both halves (1 v_perm_b32 each)
__device__ inline h2 bcast_lo(unsigned u){ return u2h(__builtin_amdgcn_perm(u, u, 0x01000100)); }
__device__ inline h2 bcast_hi(unsigned u){ return u2h(__builtin_amdgcn_perm(u, u, 0x03020302)); }

// ---- transpose_prep: fused x NCHW->NHWC f16 transpose + weight repack ----
__global__ __launch_bounds__(256) void transpose_prep(
    const float* __restrict__ x, unsigned short* __restrict__ xt,
    const float* __restrict__ w_dcn, const float* __restrict__ w_off,
    unsigned short* __restrict__ w_bf, unsigned short* __restrict__ wA)
{
    __shared__ unsigned tb[64 * 33];          // [pix][ch-pair], stride 33
    if (blockIdx.x >= B_ * 256) {             // weight-repack tail blocks
        int i = (blockIdx.x - B_ * 256) * 256 + threadIdx.x;
        if (i < 64 * CK_) {
            int o = i / CK_, r = i % CK_;
            int tap = r >> 6, c = r & 63;
            w_bf[i] = f2h(w_dcn[o * CK_ + c * 9 + tap]);
        } else {
            int j = i - 64 * CK_;             // 0 .. 32*576-1
            int o = j / CK_, r = j % CK_;
            int tap = r >> 6, c = r & 63;
            float v = (o < 27) ? w_off[o * CK_ + c * 9 + tap] : 0.f;
            wA[j] = f2h(v);
        }
        return;
    }
    int b = blockIdx.x >> 8;
    int pixbase = (blockIdx.x & 255) * 64;
    int t = threadIdx.x;
    #pragma unroll
    for (int i = 0; i < 2; ++i) {
        int idx = i * 256 + t;                // 0..511
        int cp = idx >> 4;                    // ch-pair 0..31
        int p4 = (idx & 15) * 4;              // pix 0..60 step 4
        const float* r0 = x + ((size_t)(b * C_) + 2 * cp    ) * HW_ + pixbase + p4;
        const float* r1 = x + ((size_t)(b * C_) + 2 * cp + 1) * HW_ + pixbase + p4;
        float4 f0 = *(const float4*)r0;
        float4 f1 = *(const float4*)r1;
        tb[(p4 + 0) * 33 + cp] = pkrtz(f0.x, f1.x);
        tb[(p4 + 1) * 33 + cp] = pkrtz(f0.y, f1.y);
        tb[(p4 + 2) * 33 + cp] = pkrtz(f0.z, f1.z);
        tb[(p4 + 3) * 33 + cp] = pkrtz(f0.w, f1.w);
    }
    __syncthreads();
    unsigned* xo = (unsigned*)xt + ((size_t)b * HW_ + pixbase) * 32;
    #pragma unroll
    for (int i = 0; i < 2; ++i) {
        int idx = i * 256 + t;
        int pix = idx >> 3, j = idx & 7;
        uint4 v;
        v.x = tb[pix * 33 + j * 4 + 0];
        v.y = tb[pix * 33 + j * 4 + 1];
        v.z = tb[pix * 33 + j * 4 + 2];
        v.w = tb[pix * 33 + j * 4 + 3];
        *(uint4*)(xo + pix * 32 + j * 4) = v;   // contiguous 1KB per wave-instr
    }
}

// ==== ROUND 13: dcn17 — tap-granular produce||GEMM double-buffer ===========
// r12 = 3rd occupancy null; r8 = latency null; r3/r5 = conflict null.
// Remaining theory: PHASE SERIALIZATION — produce (L1+VALU) and GEMM
// (LDS+MFMA) alternate behind barriers; per-chunk Af loads + in-order vmcnt
// drain the cross-chunk gather lookahead at every GEMM entry (why r8 nulled).
// Fix: sS double-buffered at TAP granularity (2 x 64 x 144B = 18432B, still
// under the 25344B halo union -> LDS alloc stays 32768, occupancy kept):
// body(t) = { produce tap t+1 -> buf[(t+1)&1]  ||  GEMM tap t <- buf[t&1] },
// ONE barrier per tap, no produce/GEMM barrier -> compiler interleaves
// MFMA+ds_read with blend+gather. Af register-double-buffered (loaded right
// after next tap's gathers -> in-order queue already drained past them at
// use). K-slice order ascending 0..17, blend math untouched -> bit-exact.
// Pre-commit: dur>=66 = 4th structural null -> declare floor next round.

#define PXB 128                               // bytes per staged halo pixel
#define ROWB (66 * PXB)                       // 8448 B per staged row
#define SSTRB 144                             // sS row stride bytes (2-way max)
#define SBUF (64 * SSTRB)                     // 9216 B per tap buffer

__global__ __launch_bounds__(256, 4) void dcn17(
    const unsigned short* __restrict__ xt,    // f16 NHWC
    const unsigned short* __restrict__ wA,    // offset-conv weights [32][576] f16
    const float* __restrict__ b_off,
    const unsigned short* __restrict__ w_bf,  // dcn weights [64][576] f16
    float* __restrict__ out)
{
    __shared__ __align__(16) unsigned char uni[25600];  // halo | om | sS x2
    __shared__ uint2 scr_w[576];              // 4608 B, live through Phase B
    __shared__ int   scr_o[576];              // 2304 B
    unsigned char* xrow = uni;                // 25344 B halo
    float* om = (float*)uni;                  // 7020 B after Phase A (barrier)
    unsigned char* sS = uni;                  // 2 x 9216 B in Phase B

    int tile = blockIdx.x;
    int b  = tile >> 8;
    int p0 = (tile & 255) * 64;
    int y  = p0 >> 7;
    int x0 = p0 & 127;
    int t  = threadIdx.x;
    int lane = t & 63, w = t >> 6;
    int m = lane & 15, q = lane >> 4;

    const unsigned short* xbr = xt + (size_t)(b * HW_) * 64;

    // ---- stage halo (r12-verified): chunk g of pixel c at (g^(c&7))*16 -----
    for (int i = t; i < 3 * 66 * 8; i += 256) {
        int r = i / 528;
        int rem = i - r * 528;
        int c = rem >> 3;
        int g = rem & 7;
        int yy = y - 1 + r;
        int xx = x0 - 1 + c;
        uint4 v = {0, 0, 0, 0};
        if (yy >= 0 && yy < H_ && xx >= 0 && xx < W_)
            v = *(const uint4*)(xbr + ((size_t)yy * W_ + xx) * 64 + g * 8);
        *(uint4*)(xrow + r * ROWB + c * PXB + ((g ^ (c & 7)) << 4)) = v;
    }
    __syncthreads();

    // ---- Phase A: offset conv; B-operand from swizzled LDS halo ------------
    {
        int o0c = (w & 1) * 16;
        int pxh = (w >> 1) * 32;

        f32x4 accc[2] = {};
        #pragma unroll
        for (int ky = 0; ky < 3; ++ky) {
            #pragma unroll
            for (int kx = 0; kx < 3; ++kx) {
                int s2 = (ky * 3 + kx) * 2;
                f16x8 A0 = *(const f16x8*)(wA + (o0c + m) * CK_ + s2 * 32 + q * 8);
                f16x8 A1 = *(const f16x8*)(wA + (o0c + m) * CK_ + (s2 + 1) * 32 + q * 8);
                #pragma unroll
                for (int nt = 0; nt < 2; ++nt) {
                    int c = pxh + nt * 16 + m + kx;
                    const unsigned char* p = xrow + ky * ROWB + c * PXB;
                    int off0 = (q ^ (c & 7)) << 4;
                    f16x8 b0 = *(const f16x8*)(p + off0);
                    f16x8 b1 = *(const f16x8*)(p + (off0 ^ 64));
                    accc[nt] = __builtin_amdgcn_mfma_f32_16x16x32_f16(A0, b0, accc[nt], 0, 0, 0);
                    accc[nt] = __builtin_amdgcn_mfma_f32_16x16x32_f16(A1, b1, accc[nt], 0, 0, 0);
                }
            }
        }
        __syncthreads();      // halo dead; om about to overwrite the region
        #pragma unroll
        for (int nt = 0; nt < 2; ++nt) {
            #pragma unroll
            for (int r = 0; r < 4; ++r) {
                int j = o0c + q * 4 + r;
                if (j < 27)
                    om[j * 65 + pxh + nt * 16 + m] = accc[nt][r] + b_off[j];
            }
        }
    }
    __syncthreads();

    // ---- Phase 0: offsets -> 4xf16 weights + packed offsets (LDS scr) ------
    for (int i = t; i < 576; i += 256) {
        int k = i >> 6, sp = i & 63;
        float dy = om[(2 * k)     * 65 + sp];
        float dx = om[(2 * k + 1) * 65 + sp];
        float mk = 1.f / (1.f + __expf(-om[(18 + k) * 65 + sp]));
        float py = dy + (float)(y - 1 + k / 3);
        float px = dx + (float)(x0 + sp - 1 + k % 3);
        float fy = floorf(py), fx = floorf(px);
        int iy = (int)fy, ix = (int)fx;
        float ay = py - fy, ax = px - fx;
        float wy0 = (iy >= 0  && iy < H_)     ? (1.f - ay) : 0.f;
        float wy1 = (iy >= -1 && iy < H_ - 1) ? ay         : 0.f;
        float wx0 = (ix >= 0  && ix < W_)     ? (1.f - ax) : 0.f;
        float wx1 = (ix >= -1 && ix < W_ - 1) ? ax         : 0.f;
        int iy0 = min(max(iy, 0), H_ - 1);
        int iy1 = min(max(iy + 1, 0), H_ - 1);
        int ix0 = min(max(ix, 0), W_ - 1);
        int ix1 = min(max(ix + 1, 0), W_ - 1);
        float w00 = wy0*wx0*mk, w01 = wy0*wx1*mk, w10 = wy1*wx0*mk, w11 = wy1*wx1*mk;
        uint2 wv;
        wv.x = pkrtz(w00, w01);               // lo=w00 hi=w01
        wv.y = pkrtz(w10, w11);               // lo=w10 hi=w11
        scr_w[i] = wv;
        int off00 = (iy0 * W_ + ix0) * 128;   // bytes (64ch * 2B f16)
        scr_o[i] = off00 | ((ix1 != ix0) << 22) | ((iy1 != iy0) << 23);
    }

    int o0 = w * 16;
    __syncthreads();        // scr ready; om region (sS) now free

    // ---- Phase B: tap-granular produce || GEMM, one barrier per tap --------
    int cq = lane & 7;
    int g  = lane >> 3;
    const unsigned char* xb = (const unsigned char*)xbr;
    f32x4 acc[4] = {};
    int piB = w * 8 + g;

// one produce iteration for global k (0..17): scr prefetch k+2, gather k+1,
// blend k, store into buffer (k>>1)&1. Identical math/order to dcn16.
#define PROD(K) do {                                                        \
        const int k_ = (K);                                                 \
        uint2 wC_ = {}; int pC_ = 0;                                        \
        if (k_ + 2 < 18) {                                                  \
            int P = piB + (k_ + 2) * 32;                                    \
            wC_ = scr_w[P]; pC_ = scr_o[P];                                 \
        }                                                                   \
        uint4 n00 = {}, n01 = {}, n10 = {}, n11 = {};                       \
        if (k_ + 1 < 18) {                                                  \
            const unsigned char* a0 = xb + (pB_ & 0x3FFFFF) + cq * 16;      \
            int dxb = (pB_ >> 15) & 128;                                    \
            int dyb = (pB_ >> 9)  & 16384;                                  \
            n00 = *(const uint4*)(a0);                                      \
            n01 = *(const uint4*)(a0 + dxb);                                \
            n10 = *(const uint4*)(a0 + dyb);                                \
            n11 = *(const uint4*)(a0 + dyb + dxb);                          \
        }                                                                   \
        h2 w00 = bcast_lo(wA_.x), w01 = bcast_hi(wA_.x);                    \
        h2 w10 = bcast_lo(wA_.y), w11 = bcast_hi(wA_.y);                    \
        uint4 o4; h2 r;                                                     \
        r = w00*u2h(a00.x) + w01*u2h(a01.x) + w10*u2h(a10.x) + w11*u2h(a11.x); o4.x = h2u(r); \
        r = w00*u2h(a00.y) + w01*u2h(a01.y) + w10*u2h(a10.y) + w11*u2h(a11.y); o4.y = h2u(r); \
        r = w00*u2h(a00.z) + w01*u2h(a01.z) + w10*u2h(a10.z) + w11*u2h(a11.z); o4.z = h2u(r); \
        r = w00*u2h(a00.w) + w01*u2h(a01.w) + w10*u2h(a10.w) + w11*u2h(a11.w); o4.w = h2u(r); \
        int sp_ = (piB + (k_ & 1) * 32) & 63;                               \
        *(uint4*)&sS[((k_ >> 1) & 1) * SBUF + sp_ * SSTRB + cq * 16] = o4;  \
        wA_ = wB_; wB_ = wC_; pB_ = pC_;                                    \
        a00 = n00; a01 = n01; a10 = n10; a11 = n11;                         \
    } while (0)

    // rolling pipeline init (identical to dcn16)
    uint2 wA_, wB_; int pB_;
    uint4 a00, a01, a10, a11;
    {
        wA_ = scr_w[piB];      int oo = scr_o[piB];
        wB_ = scr_w[piB + 32]; pB_ = scr_o[piB + 32];
        const unsigned char* a0 = xb + (oo & 0x3FFFFF) + cq * 16;
        int dxb = (oo >> 15) & 128;
        int dyb = (oo >> 9)  & 16384;
        a00 = *(const uint4*)(a0);
        a01 = *(const uint4*)(a0 + dxb);
        a10 = *(const uint4*)(a0 + dyb);
        a11 = *(const uint4*)(a0 + dyb + dxb);
    }

    // A-frag register double-buffer: AfC = tap tp, AfN = tap tp+1
    f16x8 AfC0 = *(const f16x8*)(w_bf + (o0 + m) * CK_ + 0 * 32 + q * 8);
    f16x8 AfC1 = *(const f16x8*)(w_bf + (o0 + m) * CK_ + 1 * 32 + q * 8);

    // prologue: produce tap 0 into buf 0
    PROD(0); PROD(1);
    __syncthreads();

    #pragma unroll
    for (int tp = 0; tp < 9; ++tp) {
        f16x8 AfN0, AfN1;
        if (tp < 8) {
            // produce tap tp+1 into buf (tp+1)&1 (gathers first...)
            PROD(2 * tp + 2);
            PROD(2 * tp + 3);
            // ...then Af(tp+1): by its use (next iter) the in-order queue has
            // already drained past it via this tap's blends -> free wait.
            AfN0 = *(const f16x8*)(w_bf + (o0 + m) * CK_ + (2 * tp + 2) * 32 + q * 8);
            AfN1 = *(const f16x8*)(w_bf + (o0 + m) * CK_ + (2 * tp + 3) * 32 + q * 8);
        }
        // GEMM tap tp from buf tp&1 (no barrier above -> interleaves with PROD)
        #pragma unroll
        for (int nt = 0; nt < 4; ++nt) {
            f16x8 bb0 = *(const f16x8*)&sS[(tp & 1) * SBUF + (nt * 16 + m) * SSTRB + q * 16];
            acc[nt] = __builtin_amdgcn_mfma_f32_16x16x32_f16(AfC0, bb0, acc[nt], 0, 0, 0);
        }
        #pragma unroll
        for (int nt = 0; nt < 4; ++nt) {
            f16x8 bb1 = *(const f16x8*)&sS[(tp & 1) * SBUF + (nt * 16 + m) * SSTRB + 64 + q * 16];
            acc[nt] = __builtin_amdgcn_mfma_f32_16x16x32_f16(AfC1, bb1, acc[nt], 0, 0, 0);
        }
        if (tp < 8) {
            __syncthreads();      // buf (tp+1)&1 ready; buf tp&1 free
            AfC0 = AfN0; AfC1 = AfN1;
        }
    }
#undef PROD

    // Epilogue: col(px)=m, row(o)=q*4+reg
    #pragma unroll
    for (int nt = 0; nt < 4; ++nt) {
        #pragma unroll
        for (int r = 0; r < 4; ++r) {
            int o = o0 + q * 4 + r;
            out[((size_t)(b * CO_ + o)) * HW_ + p0 + nt * 16 + m] = acc[nt][r];
        }
    }
}

extern "C" void kernel_launch(void* const* d_in, const int* in_sizes, int n_in,
                              void* d_out, int out_size, void* d_ws, size_t ws_size,
                              hipStream_t stream)
{
    const float* x     = (const float*)d_in[0];
    const float* w_off = (const float*)d_in[1];
    const float* b_off = (const float*)d_in[2];
    const float* w_dcn = (const float*)d_in[3];
    float* out = (float*)d_out;

    unsigned short* xt   = (unsigned short*)d_ws;                // 16.8 MB
    unsigned short* w_bf = xt + (size_t)B_ * HW_ * 64;           // 73.7 KB
    unsigned short* wA   = w_bf + 64 * CK_;                      // 36.9 KB

    transpose_prep<<<B_ * 256 + 216, 256, 0, stream>>>(x, xt, w_dcn, w_off, w_bf, wA);
    dcn17<<<B_ * 256, 256, 0, stream>>>(xt, wA, b_off, w_bf, out);
}